// Round 8
// baseline (195.668 us; speedup 1.0000x reference)
//
#include <hip/hip_runtime.h>
#include <hip/hip_bf16.h>
#include <stdint.h>

#define B_N   16
#define C_N   256
#define W_N   64
#define HW_N  4096
#define CK_N  32      // f,g channels
#define CH_N  128     // h channels
#define HWP_N 1024    // pooled spatial
#define MR_N  192     // CK+CK+CH rows in fused conv weight

typedef __attribute__((ext_vector_type(8))) short short8;
typedef __attribute__((ext_vector_type(4))) float f32x4;
typedef __attribute__((ext_vector_type(4))) unsigned uint4v;

#define MFMA(a, b, c) __builtin_amdgcn_mfma_f32_16x16x32_bf16((a), (b), (c), 0, 0, 0)

__device__ __forceinline__ unsigned short f2bf(float f) {
    union { float f; unsigned u; } v; v.f = f;
    unsigned r = v.u + 0x7FFFu + ((v.u >> 16) & 1u);   // RNE
    return (unsigned short)(r >> 16);
}
// round-half-up bf16 pair pack: 3 VALU ops (add, add, v_perm)
__device__ __forceinline__ unsigned packrn(float lo, float hi) {
    unsigned a = __float_as_uint(lo) + 0x8000u;
    unsigned b = __float_as_uint(hi) + 0x8000u;
    return __builtin_amdgcn_perm(b, a, 0x07060302);  // (a>>16)|(b&0xFFFF0000)
}
__device__ __forceinline__ short8 ld8(const void* p) {
    return *reinterpret_cast<const short8*>(p);
}

// ---------------- kernel 0: cast weights to bf16 ----------------
__global__ __launch_bounds__(256) void k_prep(
    const float* __restrict__ wf, const float* __restrict__ wg,
    const float* __restrict__ wh, const float* __restrict__ wv,
    unsigned short* __restrict__ Wc, unsigned short* __restrict__ Wv)
{
    int i = blockIdx.x * 256 + threadIdx.x;
    if (i < MR_N * C_N) {
        int r = i / C_N, c = i % C_N;
        float v = (r < 32) ? wf[r * C_N + c]
                : (r < 64) ? wg[(r - 32) * C_N + c]
                           : wh[(r - 64) * C_N + c];
        Wc[i] = f2bf(v);
    }
    if (i < C_N * CH_N) Wv[i] = f2bf(wv[i]);
}

// ---------------- kernel 1: fused conv1x1 (f,g,h) + 2x2 maxpool ----------------
// f_/g_/h_ all bf16.
__global__ __launch_bounds__(256) void k_conv_fgh(
    const float* __restrict__ x, const unsigned short* __restrict__ Wc,
    const float* __restrict__ bfp, const float* __restrict__ bgp, const float* __restrict__ bhp,
    unsigned short* __restrict__ f_, unsigned short* __restrict__ g_, unsigned short* __restrict__ h_)
{
    __shared__ __align__(16) unsigned char lds[64 * 512];
    const int T = threadIdx.x;
    const int lane = T & 63, wid = T >> 6;
    const int blk = blockIdx.x;
    const int b = blk >> 6;
    const int seg = blk & 63;
    const int rp = seg >> 1;     // pooled row 0..31
    const int half = seg & 1;    // which 32-wide half of the row pair
    const float* xb = x + (size_t)b * C_N * HW_N;

    // stage x -> LDS bf16 (transpose to [px][ch] with chunk-XOR swizzle)
    #pragma unroll
    for (int i = 0; i < 8; ++i) {
        int task = i * 256 + T;        // 0..2047 = 16 px-quads x 128 ch-pairs
        int pq = task & 15;
        int cp = task >> 4;            // channel pair 0..127
        int px0 = pq * 4;
        int row = 2 * rp + (px0 >> 5);
        int wcol = half * 32 + (px0 & 31);
        const float4 v0 = *reinterpret_cast<const float4*>(xb + (size_t)(2 * cp) * HW_N + row * W_N + wcol);
        const float4 v1 = *reinterpret_cast<const float4*>(xb + (size_t)(2 * cp + 1) * HW_N + row * W_N + wcol);
        float vlo[4] = {v0.x, v0.y, v0.z, v0.w};
        float vhi[4] = {v1.x, v1.y, v1.z, v1.w};
        int kc = cp >> 2, co = cp & 3;
        #pragma unroll
        for (int j = 0; j < 4; ++j) {
            int px = px0 + j;
            *reinterpret_cast<unsigned*>(lds + px * 512 + ((kc ^ (px & 31)) << 4) + co * 4)
                = packrn(vlo[j], vhi[j]);
        }
    }
    __syncthreads();

    const int l15 = lane & 15, quad = lane >> 4;
    f32x4 acc[3][4];
    #pragma unroll
    for (int mt = 0; mt < 3; ++mt)
        #pragma unroll
        for (int nt = 0; nt < 4; ++nt)
            acc[mt][nt] = f32x4{0.f, 0.f, 0.f, 0.f};

    const int m0base = wid * 48;
    for (int k0 = 0; k0 < 256; k0 += 32) {
        short8 afr[3];
        #pragma unroll
        for (int mt = 0; mt < 3; ++mt)
            afr[mt] = ld8(Wc + (size_t)(m0base + mt * 16 + l15) * C_N + k0 + quad * 8);
        #pragma unroll
        for (int nt = 0; nt < 4; ++nt) {
            int px = nt * 16 + l15;
            int kc = (k0 >> 3) + quad;
            short8 bfr = ld8(lds + px * 512 + ((kc ^ (px & 31)) << 4));
            #pragma unroll
            for (int mt = 0; mt < 3; ++mt)
                acc[mt][nt] = MFMA(afr[mt], bfr, acc[mt][nt]);
        }
    }

    // epilogue: bias, pool, scatter to f/g/h
    #pragma unroll
    for (int mt = 0; mt < 3; ++mt) {
        int mbase = m0base + mt * 16;
        int mrow0 = mbase + quad * 4;
        float bias[4];
        #pragma unroll
        for (int r = 0; r < 4; ++r) {
            int m = mrow0 + r;
            bias[r] = (m < 32) ? bfp[m] : (m < 64) ? bgp[m - 32] : bhp[m - 64];
        }
        if (mbase < 32) {
            #pragma unroll
            for (int nt = 0; nt < 4; ++nt) {
                int px = nt * 16 + l15;
                int p = (2 * rp + (px >> 5)) * W_N + half * 32 + (px & 31);
                uint2 u;
                u.x = packrn(acc[mt][nt][0] + bias[0], acc[mt][nt][1] + bias[1]);
                u.y = packrn(acc[mt][nt][2] + bias[2], acc[mt][nt][3] + bias[3]);
                *reinterpret_cast<uint2*>(f_ + ((size_t)b * HW_N + p) * CK_N + mrow0) = u;
            }
        } else if (mbase < 64) {
            int gc0 = mrow0 - 32;
            #pragma unroll
            for (int nt = 0; nt < 2; ++nt) {
                float pv[4];
                #pragma unroll
                for (int r = 0; r < 4; ++r) {
                    float m1 = fmaxf(acc[mt][nt][r], acc[mt][nt + 2][r]);
                    pv[r] = fmaxf(m1, __shfl_xor(m1, 1)) + bias[r];
                }
                if ((lane & 1) == 0) {
                    int kp = rp * 32 + half * 16 + ((nt * 16 + l15) >> 1);
                    uint2 u;
                    u.x = packrn(pv[0], pv[1]);
                    u.y = packrn(pv[2], pv[3]);
                    *reinterpret_cast<uint2*>(g_ + ((size_t)b * HWP_N + kp) * CK_N + gc0) = u;
                }
            }
        } else {
            int hc0 = mrow0 - 64;
            #pragma unroll
            for (int nt = 0; nt < 2; ++nt) {
                float pv[4];
                #pragma unroll
                for (int r = 0; r < 4; ++r) {
                    float m1 = fmaxf(acc[mt][nt][r], acc[mt][nt + 2][r]);
                    pv[r] = fmaxf(m1, __shfl_xor(m1, 1)) + bias[r];
                }
                #pragma unroll
                for (int r = 0; r < 4; ++r) {
                    int lo = (int)(packrn(pv[r], pv[r]) & 0xFFFFu);  // bf16 bits
                    int hi = __shfl_down(lo, 2);
                    if ((lane & 3) == 0) {
                        int kp2 = rp * 32 + half * 16 + nt * 8 + (l15 >> 1);
                        *reinterpret_cast<unsigned*>(
                            h_ + ((size_t)b * CH_N + hc0 + r) * HWP_N + kp2)
                            = (unsigned)lo | ((unsigned)hi << 16);
                    }
                }
            }
        }
    }
}

// ---------------- kernel 2: fused attention + final conv1x1 + residual ----------------
// 16 queries/wave, 4 waves/block, grid 1024 -> 4 blocks/CU. Fixed-shift softmax.
// V double-buffered in LDS (2 x [128 rows][136B]) -- verified-0-conflict layout.
// PV uses K=32 MFMA via permuted-key QK (R2).
// NEW (R8): sigma-permuted V staging kills the epilogue LDS round-trip.
// V ch c is staged at LDS row rho(c) = 32*(c>>5) + 16*((c>>2)&1) +
// 4*((c>>3)&3) + (c&3). Then oacc[2t],oacc[2t+1] hold o for ch
// 32t + 8*quad + {0..3} and {4..7} -- packrn pairs give EXACTLY the K=32
// B-fragment over ch (mirror of the R2 pfA construction). Epilogue = pack
// pfO[4], then 16 oc-tiles x 4 MFMA with Wv A-frags from global (L2-hot),
// + gamma/bias/x-residual with 64B-coalesced dword loads/stores
// (old float4 stores were 16B segments at 16KB stride). No o_lds, no
// post-loop barrier, same MFMA count, same K order -> bitwise-identical out.
__global__ __launch_bounds__(256, 4) void k_attn(
    const unsigned short* __restrict__ f_, const unsigned short* __restrict__ g_,
    const unsigned short* __restrict__ h_, const unsigned short* __restrict__ Wv,
    const float* __restrict__ bv, const float* __restrict__ x,
    const float* __restrict__ gamma_p, float* __restrict__ out)
{
    __shared__ __align__(16) unsigned char Vl[2 * 17408];
    const int T = threadIdx.x;
    const int lane = T & 63, wid = T >> 6;
    const int l15 = lane & 15, quad = lane >> 4;

    const int blk = blockIdx.x;      // 1024 = 16 b x 64 qtiles(64q)
    const int b = blk >> 6;
    const int q0w = (blk & 63) * 64 + wid * 16;
    const unsigned short* fb = f_ + (size_t)b * HW_N * CK_N;
    const unsigned short* gb = g_ + (size_t)b * HWP_N * CK_N;
    const unsigned short* hb = h_ + (size_t)b * CH_N * HWP_N;

    short8 ffr = ld8(fb + (size_t)(q0w + l15) * CK_N + quad * 8);

    const f32x4 zf = {0.f, 0.f, 0.f, 0.f};
    f32x4 oacc[8];   // [ct]; D row = permuted-ch(quad*4+r), col = query(l15)
    #pragma unroll
    for (int ct = 0; ct < 8; ++ct)
        oacc[ct] = f32x4{0.f, 0.f, 0.f, 0.f};
    float lsum = 0.f;

    // staging coords: ch rows sch+32i (i<4), 16B key-chunk skq (0-conflict)
    const int sch = T >> 3, skq = T & 7;
    // sigma-permuted LDS row base: ch sch+32i -> row rho0 + 32i
    const int rho0 = ((sch >> 2) & 1) * 16 + (sch >> 3) * 4 + (sch & 3);
    // permuted in-tile key row for QK A-operand: l15 -> 8*(l15>>2) + (l15&3)
    const int kq = ((l15 >> 2) << 3) | (l15 & 3);

    uint4 vpre[4];
    #pragma unroll
    for (int i = 0; i < 4; ++i)
        vpre[i] = *reinterpret_cast<const uint4*>(hb + (size_t)(sch + i * 32) * HWP_N + skq * 8);
    short8 gcur[4];
    #pragma unroll
    for (int kt = 0; kt < 4; ++kt)
        gcur[kt] = ld8(gb + (size_t)(((kt >> 1) << 5) + ((kt & 1) << 2) + kq) * CK_N + quad * 8);

    for (int c = 0; c < 16; ++c) {
        unsigned char* buf = Vl + (c & 1) * 17408;
        // write chunk c's V (WAR on this buffer was cleared by iter c-1's barrier)
        #pragma unroll
        for (int i = 0; i < 4; ++i) {
            unsigned char* dst = buf + (rho0 + i * 32) * 136 + skq * 16;
            *reinterpret_cast<uint2*>(dst)     = uint2{vpre[i].x, vpre[i].y};
            *reinterpret_cast<uint2*>(dst + 8) = uint2{vpre[i].z, vpre[i].w};
        }
        // issue chunk c+1 global loads (land during chunk c compute)
        if (c < 15) {
            #pragma unroll
            for (int i = 0; i < 4; ++i)
                vpre[i] = *reinterpret_cast<const uint4*>(
                    hb + (size_t)(sch + i * 32) * HWP_N + (c + 1) * 64 + skq * 8);
        }
        __syncthreads();   // buf writes visible; single barrier per chunk

        // QK: sp[kt] row (quad,r) = key (kt>>1)*32 + (kt&1)*4 + 8*quad + r, col=q(l15)
        f32x4 sp[4];
        #pragma unroll
        for (int kt = 0; kt < 4; ++kt)
            sp[kt] = MFMA(gcur[kt], ffr, zf);
        if (c < 15) {
            #pragma unroll
            for (int kt = 0; kt < 4; ++kt)
                gcur[kt] = ld8(gb + (size_t)((c + 1) * 64 + ((kt >> 1) << 5) + ((kt & 1) << 2) + kq) * CK_N + quad * 8);
        }

        // exp2 fixed shift, accumulate denom, pack straight into K=32 B-frags
        unsigned pw[8];
        float lw = 0.f;
        #pragma unroll
        for (int kt = 0; kt < 4; ++kt) {
            float p0 = __builtin_amdgcn_exp2f(sp[kt][0] * 1.44269504f - 28.85390082f);
            float p1 = __builtin_amdgcn_exp2f(sp[kt][1] * 1.44269504f - 28.85390082f);
            float p2 = __builtin_amdgcn_exp2f(sp[kt][2] * 1.44269504f - 28.85390082f);
            float p3 = __builtin_amdgcn_exp2f(sp[kt][3] * 1.44269504f - 28.85390082f);
            lw += (p0 + p1) + (p2 + p3);
            pw[2 * kt]     = packrn(p0, p1);
            pw[2 * kt + 1] = packrn(p2, p3);
        }
        lsum += lw;
        // B-frag slice t: lane quad holds P[key=t*32+8*quad+j][q=l15], j=0..7
        short8 pfA = __builtin_bit_cast(short8, uint4v{pw[0], pw[1], pw[2], pw[3]});
        short8 pfB = __builtin_bit_cast(short8, uint4v{pw[4], pw[5], pw[6], pw[7]});

        // PV: A = V_lds[row=ct*16+l15][key=t*32+quad*8+j], two b64 reads per frag
        const int vbase = l15 * 136 + quad * 16;
        #pragma unroll
        for (int ct = 0; ct < 8; ++ct) {
            const unsigned char* p = buf + vbase + ct * 2176;
            uint2 aLo0 = *reinterpret_cast<const uint2*>(p);
            uint2 aLo1 = *reinterpret_cast<const uint2*>(p + 8);
            short8 a0 = __builtin_bit_cast(short8, uint4v{aLo0.x, aLo0.y, aLo1.x, aLo1.y});
            oacc[ct] = MFMA(a0, pfA, oacc[ct]);
            uint2 aHi0 = *reinterpret_cast<const uint2*>(p + 64);
            uint2 aHi1 = *reinterpret_cast<const uint2*>(p + 72);
            short8 a1 = __builtin_bit_cast(short8, uint4v{aHi0.x, aHi0.y, aHi1.x, aHi1.y});
            oacc[ct] = MFMA(a1, pfB, oacc[ct]);
        }
    }

    // reduce denominator across quads (lanes share query = l15), scale
    lsum += __shfl_xor(lsum, 16); lsum += __shfl_xor(lsum, 32);
    const float rl = 1.f / lsum;

    // ---- pack o directly into K=32 B-frags over ch (sigma staging) ----
    // oacc[2t+h][r] = o[ch = 32t + 8*quad + 4h + r][q=l15]
    short8 pfO[4];
    #pragma unroll
    for (int t = 0; t < 4; ++t) {
        uint4v u;
        u.x = packrn(oacc[2 * t][0] * rl,     oacc[2 * t][1] * rl);
        u.y = packrn(oacc[2 * t][2] * rl,     oacc[2 * t][3] * rl);
        u.z = packrn(oacc[2 * t + 1][0] * rl, oacc[2 * t + 1][1] * rl);
        u.w = packrn(oacc[2 * t + 1][2] * rl, oacc[2 * t + 1][3] * rl);
        pfO[t] = __builtin_bit_cast(short8, u);
    }

    // ---- fused final conv: out[oc][q] for this wave's 16 q, all 256 oc ----
    // A = Wv frags (m=oc via l15), B = pfO (n=q via l15); D row=oc(quad*4+r).
    const float gamma = *gamma_p;
    const float* xb = x + (size_t)b * C_N * HW_N;
    float* outb = out + (size_t)b * C_N * HW_N;
    const int q = q0w + l15;
    #pragma unroll
    for (int ot = 0; ot < 16; ++ot) {
        f32x4 acc = zf;
        #pragma unroll
        for (int t = 0; t < 4; ++t) {
            short8 wfr = ld8(Wv + (size_t)(ot * 16 + l15) * CH_N + t * 32 + quad * 8);
            acc = MFMA(wfr, pfO[t], acc);
        }
        #pragma unroll
        for (int r = 0; r < 4; ++r) {
            int oc = ot * 16 + quad * 4 + r;
            size_t idx = (size_t)oc * HW_N + q;
            outb[idx] = gamma * (acc[r] + bv[oc]) + xb[idx];
        }
    }
}

// ---------------- launch ----------------
extern "C" void kernel_launch(void* const* d_in, const int* in_sizes, int n_in,
                              void* d_out, int out_size, void* d_ws, size_t ws_size,
                              hipStream_t stream) {
    const float* x     = (const float*)d_in[0];
    const float* wf    = (const float*)d_in[1];
    const float* bf    = (const float*)d_in[2];
    const float* wg    = (const float*)d_in[3];
    const float* bg    = (const float*)d_in[4];
    const float* wh    = (const float*)d_in[5];
    const float* bh    = (const float*)d_in[6];
    const float* wv    = (const float*)d_in[7];
    const float* bv    = (const float*)d_in[8];
    const float* gamma = (const float*)d_in[9];
    float* out = (float*)d_out;
    char* ws = (char*)d_ws;

    unsigned short* f_ = (unsigned short*)(ws);                 //  4,194,304 B
    unsigned short* g_ = (unsigned short*)(ws + 4194304);       //  1,048,576 B
    unsigned short* h_ = (unsigned short*)(ws + 5242880);       //  4,194,304 B
    unsigned short* Wc = (unsigned short*)(ws + 26214400);      //     98,304 B
    unsigned short* Wv = (unsigned short*)(ws + 26312704);      //     65,536 B

    k_prep<<<192, 256, 0, stream>>>(wf, wg, wh, wv, Wc, Wv);
    k_conv_fgh<<<1024, 256, 0, stream>>>(x, Wc, bf, bg, bh, f_, g_, h_);
    k_attn<<<1024, 256, 0, stream>>>(f_, g_, h_, Wv, bv, x, gamma, out);
}

// Round 9
// 186.367 us; speedup vs baseline: 1.0499x; 1.0499x over previous
//
#include <hip/hip_runtime.h>
#include <hip/hip_bf16.h>
#include <stdint.h>

#define B_N   16
#define C_N   256
#define W_N   64
#define HW_N  4096
#define CK_N  32      // f,g channels
#define CH_N  128     // h channels
#define HWP_N 1024    // pooled spatial
#define MR_N  192     // CK+CK+CH rows in fused conv weight

typedef __attribute__((ext_vector_type(8))) short short8;
typedef __attribute__((ext_vector_type(4))) float f32x4;
typedef __attribute__((ext_vector_type(4))) unsigned uint4v;

#define MFMA(a, b, c) __builtin_amdgcn_mfma_f32_16x16x32_bf16((a), (b), (c), 0, 0, 0)

__device__ __forceinline__ unsigned short f2bf(float f) {
    union { float f; unsigned u; } v; v.f = f;
    unsigned r = v.u + 0x7FFFu + ((v.u >> 16) & 1u);   // RNE
    return (unsigned short)(r >> 16);
}
// round-half-up bf16 pair pack: 3 VALU ops (add, add, v_perm)
__device__ __forceinline__ unsigned packrn(float lo, float hi) {
    unsigned a = __float_as_uint(lo) + 0x8000u;
    unsigned b = __float_as_uint(hi) + 0x8000u;
    return __builtin_amdgcn_perm(b, a, 0x07060302);  // (a>>16)|(b&0xFFFF0000)
}
__device__ __forceinline__ short8 ld8(const void* p) {
    return *reinterpret_cast<const short8*>(p);
}

// ---------------- kernel 0: cast weights to bf16 ----------------
__global__ __launch_bounds__(256) void k_prep(
    const float* __restrict__ wf, const float* __restrict__ wg,
    const float* __restrict__ wh, const float* __restrict__ wv,
    unsigned short* __restrict__ Wc, unsigned short* __restrict__ Wv)
{
    int i = blockIdx.x * 256 + threadIdx.x;
    if (i < MR_N * C_N) {
        int r = i / C_N, c = i % C_N;
        float v = (r < 32) ? wf[r * C_N + c]
                : (r < 64) ? wg[(r - 32) * C_N + c]
                           : wh[(r - 64) * C_N + c];
        Wc[i] = f2bf(v);
    }
    if (i < C_N * CH_N) Wv[i] = f2bf(wv[i]);
}

// ---------------- kernel 1: fused conv1x1 (f,g,h) + 2x2 maxpool ----------------
// f_/g_/h_ all bf16.
// R9: staging loads hoisted into two 8-float4 batches issued ahead of the
// pack/write phases (conv_fgh ~42us vs ~15us pipelined floor -- latency-bound
// streaming, same family as old k_out). VGPR +64 is free: occupancy is
// LDS-capped (32KB -> 4-5 blocks/CU) as long as VGPR stays <= 128.
__global__ __launch_bounds__(256) void k_conv_fgh(
    const float* __restrict__ x, const unsigned short* __restrict__ Wc,
    const float* __restrict__ bfp, const float* __restrict__ bgp, const float* __restrict__ bhp,
    unsigned short* __restrict__ f_, unsigned short* __restrict__ g_, unsigned short* __restrict__ h_)
{
    __shared__ __align__(16) unsigned char lds[64 * 512];
    const int T = threadIdx.x;
    const int lane = T & 63, wid = T >> 6;
    const int blk = blockIdx.x;
    const int b = blk >> 6;
    const int seg = blk & 63;
    const int rp = seg >> 1;     // pooled row 0..31
    const int half = seg & 1;    // which 32-wide half of the row pair
    const float* xb = x + (size_t)b * C_N * HW_N;

    // stage x -> LDS bf16 (transpose to [px][ch] with chunk-XOR swizzle)
    {
        float4 A0[4], A1[4], B0[4], B1[4];
        #pragma unroll
        for (int i = 0; i < 4; ++i) {
            int task = i * 256 + T;
            int pq = task & 15, cp = task >> 4;
            int px0 = pq * 4;
            int row = 2 * rp + (px0 >> 5);
            int wcol = half * 32 + (px0 & 31);
            const float* base = xb + (size_t)(2 * cp) * HW_N + row * W_N + wcol;
            A0[i] = *reinterpret_cast<const float4*>(base);
            A1[i] = *reinterpret_cast<const float4*>(base + HW_N);
        }
        #pragma unroll
        for (int i = 0; i < 4; ++i) {
            int task = (i + 4) * 256 + T;
            int pq = task & 15, cp = task >> 4;
            int px0 = pq * 4;
            int row = 2 * rp + (px0 >> 5);
            int wcol = half * 32 + (px0 & 31);
            const float* base = xb + (size_t)(2 * cp) * HW_N + row * W_N + wcol;
            B0[i] = *reinterpret_cast<const float4*>(base);
            B1[i] = *reinterpret_cast<const float4*>(base + HW_N);
        }
        #pragma unroll
        for (int i = 0; i < 4; ++i) {
            int task = i * 256 + T;
            int pq = task & 15, cp = task >> 4;
            int px0 = pq * 4;
            int kc = cp >> 2, co = cp & 3;
            float vlo[4] = {A0[i].x, A0[i].y, A0[i].z, A0[i].w};
            float vhi[4] = {A1[i].x, A1[i].y, A1[i].z, A1[i].w};
            #pragma unroll
            for (int j = 0; j < 4; ++j) {
                int px = px0 + j;
                *reinterpret_cast<unsigned*>(lds + px * 512 + ((kc ^ (px & 31)) << 4) + co * 4)
                    = packrn(vlo[j], vhi[j]);
            }
        }
        #pragma unroll
        for (int i = 0; i < 4; ++i) {
            int task = (i + 4) * 256 + T;
            int pq = task & 15, cp = task >> 4;
            int px0 = pq * 4;
            int kc = cp >> 2, co = cp & 3;
            float vlo[4] = {B0[i].x, B0[i].y, B0[i].z, B0[i].w};
            float vhi[4] = {B1[i].x, B1[i].y, B1[i].z, B1[i].w};
            #pragma unroll
            for (int j = 0; j < 4; ++j) {
                int px = px0 + j;
                *reinterpret_cast<unsigned*>(lds + px * 512 + ((kc ^ (px & 31)) << 4) + co * 4)
                    = packrn(vlo[j], vhi[j]);
            }
        }
    }
    __syncthreads();

    const int l15 = lane & 15, quad = lane >> 4;
    f32x4 acc[3][4];
    #pragma unroll
    for (int mt = 0; mt < 3; ++mt)
        #pragma unroll
        for (int nt = 0; nt < 4; ++nt)
            acc[mt][nt] = f32x4{0.f, 0.f, 0.f, 0.f};

    const int m0base = wid * 48;
    for (int k0 = 0; k0 < 256; k0 += 32) {
        short8 afr[3];
        #pragma unroll
        for (int mt = 0; mt < 3; ++mt)
            afr[mt] = ld8(Wc + (size_t)(m0base + mt * 16 + l15) * C_N + k0 + quad * 8);
        #pragma unroll
        for (int nt = 0; nt < 4; ++nt) {
            int px = nt * 16 + l15;
            int kc = (k0 >> 3) + quad;
            short8 bfr = ld8(lds + px * 512 + ((kc ^ (px & 31)) << 4));
            #pragma unroll
            for (int mt = 0; mt < 3; ++mt)
                acc[mt][nt] = MFMA(afr[mt], bfr, acc[mt][nt]);
        }
    }

    // epilogue: bias, pool, scatter to f/g/h
    #pragma unroll
    for (int mt = 0; mt < 3; ++mt) {
        int mbase = m0base + mt * 16;
        int mrow0 = mbase + quad * 4;
        float bias[4];
        #pragma unroll
        for (int r = 0; r < 4; ++r) {
            int m = mrow0 + r;
            bias[r] = (m < 32) ? bfp[m] : (m < 64) ? bgp[m - 32] : bhp[m - 64];
        }
        if (mbase < 32) {
            #pragma unroll
            for (int nt = 0; nt < 4; ++nt) {
                int px = nt * 16 + l15;
                int p = (2 * rp + (px >> 5)) * W_N + half * 32 + (px & 31);
                uint2 u;
                u.x = packrn(acc[mt][nt][0] + bias[0], acc[mt][nt][1] + bias[1]);
                u.y = packrn(acc[mt][nt][2] + bias[2], acc[mt][nt][3] + bias[3]);
                *reinterpret_cast<uint2*>(f_ + ((size_t)b * HW_N + p) * CK_N + mrow0) = u;
            }
        } else if (mbase < 64) {
            int gc0 = mrow0 - 32;
            #pragma unroll
            for (int nt = 0; nt < 2; ++nt) {
                float pv[4];
                #pragma unroll
                for (int r = 0; r < 4; ++r) {
                    float m1 = fmaxf(acc[mt][nt][r], acc[mt][nt + 2][r]);
                    pv[r] = fmaxf(m1, __shfl_xor(m1, 1)) + bias[r];
                }
                if ((lane & 1) == 0) {
                    int kp = rp * 32 + half * 16 + ((nt * 16 + l15) >> 1);
                    uint2 u;
                    u.x = packrn(pv[0], pv[1]);
                    u.y = packrn(pv[2], pv[3]);
                    *reinterpret_cast<uint2*>(g_ + ((size_t)b * HWP_N + kp) * CK_N + gc0) = u;
                }
            }
        } else {
            int hc0 = mrow0 - 64;
            #pragma unroll
            for (int nt = 0; nt < 2; ++nt) {
                float pv[4];
                #pragma unroll
                for (int r = 0; r < 4; ++r) {
                    float m1 = fmaxf(acc[mt][nt][r], acc[mt][nt + 2][r]);
                    pv[r] = fmaxf(m1, __shfl_xor(m1, 1)) + bias[r];
                }
                #pragma unroll
                for (int r = 0; r < 4; ++r) {
                    int lo = (int)(packrn(pv[r], pv[r]) & 0xFFFFu);  // bf16 bits
                    int hi = __shfl_down(lo, 2);
                    if ((lane & 3) == 0) {
                        int kp2 = rp * 32 + half * 16 + nt * 8 + (l15 >> 1);
                        *reinterpret_cast<unsigned*>(
                            h_ + ((size_t)b * CH_N + hc0 + r) * HWP_N + kp2)
                            = (unsigned)lo | ((unsigned)hi << 16);
                    }
                }
            }
        }
    }
}

// ---------------- kernel 2: fused attention + final conv1x1 + residual ----------------
// R7 structure (verified 56.4us, bit-exact): 16 queries/wave, 4 waves/block,
// grid 1024 -> 4 blocks/CU. Fixed-shift softmax. V double-buffered in LDS
// (2 x [128ch][136B]) -- verified-0-conflict layout. PV uses K=32 MFMA via
// permuted-key QK (R2). k_out fused as epilogue via o_lds [64px][264B]
// (stride 264 = 256B payload + 8 pad; fits in Vl buffer 0 = 17408B).
// NOTE (R8 ledger): replacing o_lds with in-register pfO B-frags + M=256/N=16
// per-wave conv REGRESSED 56->71us (one fresh L2 Wv load per MFMA, 4x Wv
// traffic/wave, 4x store instruction count). Epilogue must keep N>=64/wave.
__global__ __launch_bounds__(256, 4) void k_attn(
    const unsigned short* __restrict__ f_, const unsigned short* __restrict__ g_,
    const unsigned short* __restrict__ h_, const unsigned short* __restrict__ Wv,
    const float* __restrict__ bv, const float* __restrict__ x,
    const float* __restrict__ gamma_p, float* __restrict__ out)
{
    __shared__ __align__(16) unsigned char Vl[2 * 17408];
    const int T = threadIdx.x;
    const int lane = T & 63, wid = T >> 6;
    const int l15 = lane & 15, quad = lane >> 4;

    const int blk = blockIdx.x;      // 1024 = 16 b x 64 qtiles(64q)
    const int b = blk >> 6;
    const int q0w = (blk & 63) * 64 + wid * 16;
    const unsigned short* fb = f_ + (size_t)b * HW_N * CK_N;
    const unsigned short* gb = g_ + (size_t)b * HWP_N * CK_N;
    const unsigned short* hb = h_ + (size_t)b * CH_N * HWP_N;

    short8 ffr = ld8(fb + (size_t)(q0w + l15) * CK_N + quad * 8);

    const f32x4 zf = {0.f, 0.f, 0.f, 0.f};
    f32x4 oacc[8];   // [ct]; D row = ch(quad*4+r), col = query(l15)
    #pragma unroll
    for (int ct = 0; ct < 8; ++ct)
        oacc[ct] = f32x4{0.f, 0.f, 0.f, 0.f};
    float lsum = 0.f;

    // staging coords: ch rows sch+32i (i<4), 16B key-chunk skq (0-conflict)
    const int sch = T >> 3, skq = T & 7;
    // permuted in-tile key row for QK A-operand: l15 -> 8*(l15>>2) + (l15&3)
    const int kq = ((l15 >> 2) << 3) | (l15 & 3);

    uint4 vpre[4];
    #pragma unroll
    for (int i = 0; i < 4; ++i)
        vpre[i] = *reinterpret_cast<const uint4*>(hb + (size_t)(sch + i * 32) * HWP_N + skq * 8);
    short8 gcur[4];
    #pragma unroll
    for (int kt = 0; kt < 4; ++kt)
        gcur[kt] = ld8(gb + (size_t)(((kt >> 1) << 5) + ((kt & 1) << 2) + kq) * CK_N + quad * 8);

    for (int c = 0; c < 16; ++c) {
        unsigned char* buf = Vl + (c & 1) * 17408;
        // write chunk c's V (WAR on this buffer was cleared by iter c-1's barrier)
        #pragma unroll
        for (int i = 0; i < 4; ++i) {
            unsigned char* dst = buf + (sch + i * 32) * 136 + skq * 16;
            *reinterpret_cast<uint2*>(dst)     = uint2{vpre[i].x, vpre[i].y};
            *reinterpret_cast<uint2*>(dst + 8) = uint2{vpre[i].z, vpre[i].w};
        }
        // issue chunk c+1 global loads (land during chunk c compute)
        if (c < 15) {
            #pragma unroll
            for (int i = 0; i < 4; ++i)
                vpre[i] = *reinterpret_cast<const uint4*>(
                    hb + (size_t)(sch + i * 32) * HWP_N + (c + 1) * 64 + skq * 8);
        }
        __syncthreads();   // buf writes visible; single barrier per chunk

        // QK: sp[kt] row (quad,r) = key (kt>>1)*32 + (kt&1)*4 + 8*quad + r, col=q(l15)
        f32x4 sp[4];
        #pragma unroll
        for (int kt = 0; kt < 4; ++kt)
            sp[kt] = MFMA(gcur[kt], ffr, zf);
        if (c < 15) {
            #pragma unroll
            for (int kt = 0; kt < 4; ++kt)
                gcur[kt] = ld8(gb + (size_t)((c + 1) * 64 + ((kt >> 1) << 5) + ((kt & 1) << 2) + kq) * CK_N + quad * 8);
        }

        // exp2 fixed shift, accumulate denom, pack straight into K=32 B-frags
        unsigned pw[8];
        float lw = 0.f;
        #pragma unroll
        for (int kt = 0; kt < 4; ++kt) {
            float p0 = __builtin_amdgcn_exp2f(sp[kt][0] * 1.44269504f - 28.85390082f);
            float p1 = __builtin_amdgcn_exp2f(sp[kt][1] * 1.44269504f - 28.85390082f);
            float p2 = __builtin_amdgcn_exp2f(sp[kt][2] * 1.44269504f - 28.85390082f);
            float p3 = __builtin_amdgcn_exp2f(sp[kt][3] * 1.44269504f - 28.85390082f);
            lw += (p0 + p1) + (p2 + p3);
            pw[2 * kt]     = packrn(p0, p1);
            pw[2 * kt + 1] = packrn(p2, p3);
        }
        lsum += lw;
        // B-frag slice t: lane quad holds P[key=t*32+8*quad+j][q=l15], j=0..7
        short8 pfA = __builtin_bit_cast(short8, uint4v{pw[0], pw[1], pw[2], pw[3]});
        short8 pfB = __builtin_bit_cast(short8, uint4v{pw[4], pw[5], pw[6], pw[7]});

        // PV: A = V[ch=ct*16+l15][key=t*32+quad*8+j], two b64 reads per frag
        const int vbase = l15 * 136 + quad * 16;
        #pragma unroll
        for (int ct = 0; ct < 8; ++ct) {
            const unsigned char* p = buf + vbase + ct * 2176;
            uint2 aLo0 = *reinterpret_cast<const uint2*>(p);
            uint2 aLo1 = *reinterpret_cast<const uint2*>(p + 8);
            short8 a0 = __builtin_bit_cast(short8, uint4v{aLo0.x, aLo0.y, aLo1.x, aLo1.y});
            oacc[ct] = MFMA(a0, pfA, oacc[ct]);
            uint2 aHi0 = *reinterpret_cast<const uint2*>(p + 64);
            uint2 aHi1 = *reinterpret_cast<const uint2*>(p + 72);
            short8 a1 = __builtin_bit_cast(short8, uint4v{aHi0.x, aHi0.y, aHi1.x, aHi1.y});
            oacc[ct] = MFMA(a1, pfB, oacc[ct]);
        }
    }

    // reduce denominator across quads (lanes share query = l15), scale
    lsum += __shfl_xor(lsum, 16); lsum += __shfl_xor(lsum, 32);
    const float rl = 1.f / lsum;

    // ---- pack o (bf16, same rounding as before) into LDS [64px][264B] ----
    // Reuses Vl buffer 0 (0..16895 < 17408). No barrier needed first: after
    // chunk 15's in-loop barrier every wave only reads buffer 1 (17408..).
    unsigned char* o_lds = Vl;
    {
        const int row = wid * 16 + l15;   // block-local px
        #pragma unroll
        for (int ct = 0; ct < 8; ++ct) {
            uint2 u;
            u.x = packrn(oacc[ct][0] * rl, oacc[ct][1] * rl);
            u.y = packrn(oacc[ct][2] * rl, oacc[ct][3] * rl);
            *reinterpret_cast<uint2*>(o_lds + row * 264 + (ct * 16 + quad * 4) * 2) = u;
        }
    }
    __syncthreads();   // o_lds visible to all waves (cross-wave px reads)

    // ---- fused final conv: wave wid does oc [wid*64, wid*64+64) x 64 px ----
    const int pxb = (blk & 63) * 64;   // global px base of this block
    const int oc0 = wid * 64;
    f32x4 acc2[4][4];   // [mt][nt]; D row=px(quad*4+r), col=oc(l15)
    #pragma unroll
    for (int mt = 0; mt < 4; ++mt)
        #pragma unroll
        for (int nt = 0; nt < 4; ++nt)
            acc2[mt][nt] = f32x4{0.f, 0.f, 0.f, 0.f};

    #pragma unroll
    for (int k0 = 0; k0 < 128; k0 += 32) {
        short8 ofr[4];   // o A-frags: row px=nt*16+l15, k=k0+quad*8..+7
        #pragma unroll
        for (int nt = 0; nt < 4; ++nt) {
            const unsigned char* p = o_lds + (nt * 16 + l15) * 264 + k0 * 2 + quad * 16;
            uint2 a0 = *reinterpret_cast<const uint2*>(p);
            uint2 a1 = *reinterpret_cast<const uint2*>(p + 8);
            ofr[nt] = __builtin_bit_cast(short8, uint4v{a0.x, a0.y, a1.x, a1.y});
        }
        #pragma unroll
        for (int mt = 0; mt < 4; ++mt) {
            short8 wfr = ld8(Wv + (size_t)(oc0 + mt * 16 + l15) * CH_N + k0 + quad * 8);
            #pragma unroll
            for (int nt = 0; nt < 4; ++nt)
                acc2[mt][nt] = MFMA(ofr[nt], wfr, acc2[mt][nt]);  // A=o(px), B=Wv(oc)
        }
    }

    const float gamma = *gamma_p;
    const float* xb = x + (size_t)b * C_N * HW_N;
    float* outb = out + (size_t)b * C_N * HW_N;
    #pragma unroll
    for (int mt = 0; mt < 4; ++mt) {
        int oc = oc0 + mt * 16 + l15;
        float bvv = bv[oc];
        #pragma unroll
        for (int nt = 0; nt < 4; ++nt) {
            size_t base = (size_t)oc * HW_N + pxb + nt * 16 + quad * 4;
            float4 xv = *reinterpret_cast<const float4*>(xb + base);
            float4 ov;
            ov.x = gamma * (acc2[mt][nt][0] + bvv) + xv.x;
            ov.y = gamma * (acc2[mt][nt][1] + bvv) + xv.y;
            ov.z = gamma * (acc2[mt][nt][2] + bvv) + xv.z;
            ov.w = gamma * (acc2[mt][nt][3] + bvv) + xv.w;
            *reinterpret_cast<float4*>(outb + base) = ov;
        }
    }
}

// ---------------- launch ----------------
extern "C" void kernel_launch(void* const* d_in, const int* in_sizes, int n_in,
                              void* d_out, int out_size, void* d_ws, size_t ws_size,
                              hipStream_t stream) {
    const float* x     = (const float*)d_in[0];
    const float* wf    = (const float*)d_in[1];
    const float* bf    = (const float*)d_in[2];
    const float* wg    = (const float*)d_in[3];
    const float* bg    = (const float*)d_in[4];
    const float* wh    = (const float*)d_in[5];
    const float* bh    = (const float*)d_in[6];
    const float* wv    = (const float*)d_in[7];
    const float* bv    = (const float*)d_in[8];
    const float* gamma = (const float*)d_in[9];
    float* out = (float*)d_out;
    char* ws = (char*)d_ws;

    unsigned short* f_ = (unsigned short*)(ws);                 //  4,194,304 B
    unsigned short* g_ = (unsigned short*)(ws + 4194304);       //  1,048,576 B
    unsigned short* h_ = (unsigned short*)(ws + 5242880);       //  4,194,304 B
    unsigned short* Wc = (unsigned short*)(ws + 26214400);      //     98,304 B
    unsigned short* Wv = (unsigned short*)(ws + 26312704);      //     65,536 B

    k_prep<<<192, 256, 0, stream>>>(wf, wg, wh, wv, Wc, Wv);
    k_conv_fgh<<<1024, 256, 0, stream>>>(x, Wc, bf, bg, bh, f_, g_, h_);
    k_attn<<<1024, 256, 0, stream>>>(f_, g_, h_, Wv, bv, x, gamma, out);
}

// Round 10
// 185.353 us; speedup vs baseline: 1.0557x; 1.0055x over previous
//
#include <hip/hip_runtime.h>
#include <hip/hip_bf16.h>
#include <stdint.h>

#define B_N   16
#define C_N   256
#define W_N   64
#define HW_N  4096
#define CK_N  32      // f,g channels
#define CH_N  128     // h channels
#define HWP_N 1024    // pooled spatial
#define MR_N  192     // CK+CK+CH rows in fused conv weight

typedef __attribute__((ext_vector_type(8))) short short8;
typedef __attribute__((ext_vector_type(4))) float f32x4;
typedef __attribute__((ext_vector_type(4))) unsigned uint4v;

#define MFMA(a, b, c) __builtin_amdgcn_mfma_f32_16x16x32_bf16((a), (b), (c), 0, 0, 0)

__device__ __forceinline__ unsigned short f2bf(float f) {
    union { float f; unsigned u; } v; v.f = f;
    unsigned r = v.u + 0x7FFFu + ((v.u >> 16) & 1u);   // RNE
    return (unsigned short)(r >> 16);
}
// round-half-up bf16 pair pack: 3 VALU ops (add, add, v_perm)
__device__ __forceinline__ unsigned packrn(float lo, float hi) {
    unsigned a = __float_as_uint(lo) + 0x8000u;
    unsigned b = __float_as_uint(hi) + 0x8000u;
    return __builtin_amdgcn_perm(b, a, 0x07060302);  // (a>>16)|(b&0xFFFF0000)
}
__device__ __forceinline__ short8 ld8(const void* p) {
    return *reinterpret_cast<const short8*>(p);
}

// ---------------- kernel 0: cast weights to bf16 ----------------
__global__ __launch_bounds__(256) void k_prep(
    const float* __restrict__ wf, const float* __restrict__ wg,
    const float* __restrict__ wh, const float* __restrict__ wv,
    unsigned short* __restrict__ Wc, unsigned short* __restrict__ Wv)
{
    int i = blockIdx.x * 256 + threadIdx.x;
    if (i < MR_N * C_N) {
        int r = i / C_N, c = i % C_N;
        float v = (r < 32) ? wf[r * C_N + c]
                : (r < 64) ? wg[(r - 32) * C_N + c]
                           : wh[(r - 64) * C_N + c];
        Wc[i] = f2bf(v);
    }
    if (i < C_N * CH_N) Wv[i] = f2bf(wv[i]);
}

// ---------------- kernel 1: fused conv1x1 (f,g,h) + 2x2 maxpool ----------------
// f_/g_/h_ all bf16. (R7 form; R9's hand-hoisted staging was neutral-to-
// negative -- compiler already schedules the unrolled loads.)
__global__ __launch_bounds__(256) void k_conv_fgh(
    const float* __restrict__ x, const unsigned short* __restrict__ Wc,
    const float* __restrict__ bfp, const float* __restrict__ bgp, const float* __restrict__ bhp,
    unsigned short* __restrict__ f_, unsigned short* __restrict__ g_, unsigned short* __restrict__ h_)
{
    __shared__ __align__(16) unsigned char lds[64 * 512];
    const int T = threadIdx.x;
    const int lane = T & 63, wid = T >> 6;
    const int blk = blockIdx.x;
    const int b = blk >> 6;
    const int seg = blk & 63;
    const int rp = seg >> 1;     // pooled row 0..31
    const int half = seg & 1;    // which 32-wide half of the row pair
    const float* xb = x + (size_t)b * C_N * HW_N;

    // stage x -> LDS bf16 (transpose to [px][ch] with chunk-XOR swizzle)
    #pragma unroll
    for (int i = 0; i < 8; ++i) {
        int task = i * 256 + T;        // 0..2047 = 16 px-quads x 128 ch-pairs
        int pq = task & 15;
        int cp = task >> 4;            // channel pair 0..127
        int px0 = pq * 4;
        int row = 2 * rp + (px0 >> 5);
        int wcol = half * 32 + (px0 & 31);
        const float4 v0 = *reinterpret_cast<const float4*>(xb + (size_t)(2 * cp) * HW_N + row * W_N + wcol);
        const float4 v1 = *reinterpret_cast<const float4*>(xb + (size_t)(2 * cp + 1) * HW_N + row * W_N + wcol);
        float vlo[4] = {v0.x, v0.y, v0.z, v0.w};
        float vhi[4] = {v1.x, v1.y, v1.z, v1.w};
        int kc = cp >> 2, co = cp & 3;
        #pragma unroll
        for (int j = 0; j < 4; ++j) {
            int px = px0 + j;
            *reinterpret_cast<unsigned*>(lds + px * 512 + ((kc ^ (px & 31)) << 4) + co * 4)
                = packrn(vlo[j], vhi[j]);
        }
    }
    __syncthreads();

    const int l15 = lane & 15, quad = lane >> 4;
    f32x4 acc[3][4];
    #pragma unroll
    for (int mt = 0; mt < 3; ++mt)
        #pragma unroll
        for (int nt = 0; nt < 4; ++nt)
            acc[mt][nt] = f32x4{0.f, 0.f, 0.f, 0.f};

    const int m0base = wid * 48;
    for (int k0 = 0; k0 < 256; k0 += 32) {
        short8 afr[3];
        #pragma unroll
        for (int mt = 0; mt < 3; ++mt)
            afr[mt] = ld8(Wc + (size_t)(m0base + mt * 16 + l15) * C_N + k0 + quad * 8);
        #pragma unroll
        for (int nt = 0; nt < 4; ++nt) {
            int px = nt * 16 + l15;
            int kc = (k0 >> 3) + quad;
            short8 bfr = ld8(lds + px * 512 + ((kc ^ (px & 31)) << 4));
            #pragma unroll
            for (int mt = 0; mt < 3; ++mt)
                acc[mt][nt] = MFMA(afr[mt], bfr, acc[mt][nt]);
        }
    }

    // epilogue: bias, pool, scatter to f/g/h
    #pragma unroll
    for (int mt = 0; mt < 3; ++mt) {
        int mbase = m0base + mt * 16;
        int mrow0 = mbase + quad * 4;
        float bias[4];
        #pragma unroll
        for (int r = 0; r < 4; ++r) {
            int m = mrow0 + r;
            bias[r] = (m < 32) ? bfp[m] : (m < 64) ? bgp[m - 32] : bhp[m - 64];
        }
        if (mbase < 32) {
            #pragma unroll
            for (int nt = 0; nt < 4; ++nt) {
                int px = nt * 16 + l15;
                int p = (2 * rp + (px >> 5)) * W_N + half * 32 + (px & 31);
                uint2 u;
                u.x = packrn(acc[mt][nt][0] + bias[0], acc[mt][nt][1] + bias[1]);
                u.y = packrn(acc[mt][nt][2] + bias[2], acc[mt][nt][3] + bias[3]);
                *reinterpret_cast<uint2*>(f_ + ((size_t)b * HW_N + p) * CK_N + mrow0) = u;
            }
        } else if (mbase < 64) {
            int gc0 = mrow0 - 32;
            #pragma unroll
            for (int nt = 0; nt < 2; ++nt) {
                float pv[4];
                #pragma unroll
                for (int r = 0; r < 4; ++r) {
                    float m1 = fmaxf(acc[mt][nt][r], acc[mt][nt + 2][r]);
                    pv[r] = fmaxf(m1, __shfl_xor(m1, 1)) + bias[r];
                }
                if ((lane & 1) == 0) {
                    int kp = rp * 32 + half * 16 + ((nt * 16 + l15) >> 1);
                    uint2 u;
                    u.x = packrn(pv[0], pv[1]);
                    u.y = packrn(pv[2], pv[3]);
                    *reinterpret_cast<uint2*>(g_ + ((size_t)b * HWP_N + kp) * CK_N + gc0) = u;
                }
            }
        } else {
            int hc0 = mrow0 - 64;
            #pragma unroll
            for (int nt = 0; nt < 2; ++nt) {
                float pv[4];
                #pragma unroll
                for (int r = 0; r < 4; ++r) {
                    float m1 = fmaxf(acc[mt][nt][r], acc[mt][nt + 2][r]);
                    pv[r] = fmaxf(m1, __shfl_xor(m1, 1)) + bias[r];
                }
                #pragma unroll
                for (int r = 0; r < 4; ++r) {
                    int lo = (int)(packrn(pv[r], pv[r]) & 0xFFFFu);  // bf16 bits
                    int hi = __shfl_down(lo, 2);
                    if ((lane & 3) == 0) {
                        int kp2 = rp * 32 + half * 16 + nt * 8 + (l15 >> 1);
                        *reinterpret_cast<unsigned*>(
                            h_ + ((size_t)b * CH_N + hc0 + r) * HWP_N + kp2)
                            = (unsigned)lo | ((unsigned)hi << 16);
                    }
                }
            }
        }
    }
}

// ---------------- kernel 2: fused attention + final conv1x1 + residual ----------------
// R10: 8 waves x 512 threads, 128 q/block, grid 512. Per-wave code identical
// to the verified R7 structure (16 q/wave, K=32 PV via permuted-key QK,
// V dbuf 2 x [128ch][136B] 0-conflict). Rationale: R7 ran 4 blocks/CU = only
// 4 waves/SIMD theoretical (occ 30%); MfmaUtil/VALUBusy were 4-8x their
// op-count minima = latency-bound from thin interleave. Same LDS (34.8KB) at
// 512 threads -> 4 blocks/CU = 32 waves/CU (8/SIMD max), VGPR must stay <=64
// (R7 measured exactly 64; vpre shrinks 4->2 so headroom improves).
// V staging per q halves (one 16KB stage serves 128 q).
// Epilogue: o_lds [128px][264B] = 33792B fits Vl (34816B) but overlaps
// buffer 1 -> one extra barrier after the KV loop before the o-pack.
// 8 waves split conv as 2 px-halves x 4 oc-quarters, each = the verified
// 64oc x 64px x K=128 GEMM.
__global__ __launch_bounds__(512, 4) void k_attn(
    const unsigned short* __restrict__ f_, const unsigned short* __restrict__ g_,
    const unsigned short* __restrict__ h_, const unsigned short* __restrict__ Wv,
    const float* __restrict__ bv, const float* __restrict__ x,
    const float* __restrict__ gamma_p, float* __restrict__ out)
{
    __shared__ __align__(16) unsigned char Vl[2 * 17408];
    const int T = threadIdx.x;
    const int lane = T & 63, wid = T >> 6;          // wid 0..7
    const int l15 = lane & 15, quad = lane >> 4;

    const int blk = blockIdx.x;      // 512 = 16 b x 32 qtiles(128q)
    const int b = blk >> 5;
    const int q0w = (blk & 31) * 128 + wid * 16;
    const unsigned short* fb = f_ + (size_t)b * HW_N * CK_N;
    const unsigned short* gb = g_ + (size_t)b * HWP_N * CK_N;
    const unsigned short* hb = h_ + (size_t)b * CH_N * HWP_N;

    short8 ffr = ld8(fb + (size_t)(q0w + l15) * CK_N + quad * 8);

    const f32x4 zf = {0.f, 0.f, 0.f, 0.f};
    f32x4 oacc[8];   // [ct]; D row = ch(quad*4+r), col = query(l15)
    #pragma unroll
    for (int ct = 0; ct < 8; ++ct)
        oacc[ct] = f32x4{0.f, 0.f, 0.f, 0.f};
    float lsum = 0.f;

    // staging coords (512 threads): ch rows sch+64i (i<2), 16B key-chunk skq.
    // Per-16-lane bank coverage identical to the verified 256-thread pattern.
    const int sch = T >> 3, skq = T & 7;            // sch 0..63
    // permuted in-tile key row for QK A-operand: l15 -> 8*(l15>>2) + (l15&3)
    const int kq = ((l15 >> 2) << 3) | (l15 & 3);

    uint4 vpre[2];
    #pragma unroll
    for (int i = 0; i < 2; ++i)
        vpre[i] = *reinterpret_cast<const uint4*>(hb + (size_t)(sch + i * 64) * HWP_N + skq * 8);
    short8 gcur[4];
    #pragma unroll
    for (int kt = 0; kt < 4; ++kt)
        gcur[kt] = ld8(gb + (size_t)(((kt >> 1) << 5) + ((kt & 1) << 2) + kq) * CK_N + quad * 8);

    for (int c = 0; c < 16; ++c) {
        unsigned char* buf = Vl + (c & 1) * 17408;
        // write chunk c's V (WAR on this buffer was cleared by iter c-1's barrier)
        #pragma unroll
        for (int i = 0; i < 2; ++i) {
            unsigned char* dst = buf + (sch + i * 64) * 136 + skq * 16;
            *reinterpret_cast<uint2*>(dst)     = uint2{vpre[i].x, vpre[i].y};
            *reinterpret_cast<uint2*>(dst + 8) = uint2{vpre[i].z, vpre[i].w};
        }
        // issue chunk c+1 global loads (land during chunk c compute)
        if (c < 15) {
            #pragma unroll
            for (int i = 0; i < 2; ++i)
                vpre[i] = *reinterpret_cast<const uint4*>(
                    hb + (size_t)(sch + i * 64) * HWP_N + (c + 1) * 64 + skq * 8);
        }
        __syncthreads();   // buf writes visible; single barrier per chunk

        // QK: sp[kt] row (quad,r) = key (kt>>1)*32 + (kt&1)*4 + 8*quad + r, col=q(l15)
        f32x4 sp[4];
        #pragma unroll
        for (int kt = 0; kt < 4; ++kt)
            sp[kt] = MFMA(gcur[kt], ffr, zf);
        if (c < 15) {
            #pragma unroll
            for (int kt = 0; kt < 4; ++kt)
                gcur[kt] = ld8(gb + (size_t)((c + 1) * 64 + ((kt >> 1) << 5) + ((kt & 1) << 2) + kq) * CK_N + quad * 8);
        }

        // exp2 fixed shift, accumulate denom, pack straight into K=32 B-frags
        unsigned pw[8];
        float lw = 0.f;
        #pragma unroll
        for (int kt = 0; kt < 4; ++kt) {
            float p0 = __builtin_amdgcn_exp2f(sp[kt][0] * 1.44269504f - 28.85390082f);
            float p1 = __builtin_amdgcn_exp2f(sp[kt][1] * 1.44269504f - 28.85390082f);
            float p2 = __builtin_amdgcn_exp2f(sp[kt][2] * 1.44269504f - 28.85390082f);
            float p3 = __builtin_amdgcn_exp2f(sp[kt][3] * 1.44269504f - 28.85390082f);
            lw += (p0 + p1) + (p2 + p3);
            pw[2 * kt]     = packrn(p0, p1);
            pw[2 * kt + 1] = packrn(p2, p3);
        }
        lsum += lw;
        // B-frag slice t: lane quad holds P[key=t*32+8*quad+j][q=l15], j=0..7
        short8 pfA = __builtin_bit_cast(short8, uint4v{pw[0], pw[1], pw[2], pw[3]});
        short8 pfB = __builtin_bit_cast(short8, uint4v{pw[4], pw[5], pw[6], pw[7]});

        // PV: A = V[ch=ct*16+l15][key=t*32+quad*8+j], two b64 reads per frag
        const int vbase = l15 * 136 + quad * 16;
        #pragma unroll
        for (int ct = 0; ct < 8; ++ct) {
            const unsigned char* p = buf + vbase + ct * 2176;
            uint2 aLo0 = *reinterpret_cast<const uint2*>(p);
            uint2 aLo1 = *reinterpret_cast<const uint2*>(p + 8);
            short8 a0 = __builtin_bit_cast(short8, uint4v{aLo0.x, aLo0.y, aLo1.x, aLo1.y});
            oacc[ct] = MFMA(a0, pfA, oacc[ct]);
            uint2 aHi0 = *reinterpret_cast<const uint2*>(p + 64);
            uint2 aHi1 = *reinterpret_cast<const uint2*>(p + 72);
            short8 a1 = __builtin_bit_cast(short8, uint4v{aHi0.x, aHi0.y, aHi1.x, aHi1.y});
            oacc[ct] = MFMA(a1, pfB, oacc[ct]);
        }
    }

    // reduce denominator across quads (lanes share query = l15), scale
    lsum += __shfl_xor(lsum, 16); lsum += __shfl_xor(lsum, 32);
    const float rl = 1.f / lsum;

    // o_lds spans both V buffers now (128 rows x 264B = 33792B) -> all waves
    // must be done reading buffer 1 (chunk 15's PV) before the o writes.
    __syncthreads();

    // ---- pack o (bf16, same rounding) into LDS [128px][264B] ----
    unsigned char* o_lds = Vl;
    {
        const int row = wid * 16 + l15;   // block-local px 0..127
        #pragma unroll
        for (int ct = 0; ct < 8; ++ct) {
            uint2 u;
            u.x = packrn(oacc[ct][0] * rl, oacc[ct][1] * rl);
            u.y = packrn(oacc[ct][2] * rl, oacc[ct][3] * rl);
            *reinterpret_cast<uint2*>(o_lds + row * 264 + (ct * 16 + quad * 4) * 2) = u;
        }
    }
    __syncthreads();   // o_lds visible to all waves (cross-wave px reads)

    // ---- fused final conv: wave = (px-half, oc-quarter); 64oc x 64px each ----
    const int pxb = (blk & 31) * 128;  // global px base of this block
    const int lp0 = (wid >> 2) * 64;   // local px base for this wave
    const int oc0 = (wid & 3) * 64;
    f32x4 acc2[4][4];   // [mt][nt]; D row=px(quad*4+r), col=oc(l15)
    #pragma unroll
    for (int mt = 0; mt < 4; ++mt)
        #pragma unroll
        for (int nt = 0; nt < 4; ++nt)
            acc2[mt][nt] = f32x4{0.f, 0.f, 0.f, 0.f};

    #pragma unroll
    for (int k0 = 0; k0 < 128; k0 += 32) {
        short8 ofr[4];   // o A-frags: row px=lp0+nt*16+l15, k=k0+quad*8..+7
        #pragma unroll
        for (int nt = 0; nt < 4; ++nt) {
            const unsigned char* p = o_lds + (lp0 + nt * 16 + l15) * 264 + k0 * 2 + quad * 16;
            uint2 a0 = *reinterpret_cast<const uint2*>(p);
            uint2 a1 = *reinterpret_cast<const uint2*>(p + 8);
            ofr[nt] = __builtin_bit_cast(short8, uint4v{a0.x, a0.y, a1.x, a1.y});
        }
        #pragma unroll
        for (int mt = 0; mt < 4; ++mt) {
            short8 wfr = ld8(Wv + (size_t)(oc0 + mt * 16 + l15) * CH_N + k0 + quad * 8);
            #pragma unroll
            for (int nt = 0; nt < 4; ++nt)
                acc2[mt][nt] = MFMA(ofr[nt], wfr, acc2[mt][nt]);  // A=o(px), B=Wv(oc)
        }
    }

    const float gamma = *gamma_p;
    const float* xb = x + (size_t)b * C_N * HW_N;
    float* outb = out + (size_t)b * C_N * HW_N;
    #pragma unroll
    for (int mt = 0; mt < 4; ++mt) {
        int oc = oc0 + mt * 16 + l15;
        float bvv = bv[oc];
        #pragma unroll
        for (int nt = 0; nt < 4; ++nt) {
            size_t base = (size_t)oc * HW_N + pxb + lp0 + nt * 16 + quad * 4;
            float4 xv = *reinterpret_cast<const float4*>(xb + base);
            float4 ov;
            ov.x = gamma * (acc2[mt][nt][0] + bvv) + xv.x;
            ov.y = gamma * (acc2[mt][nt][1] + bvv) + xv.y;
            ov.z = gamma * (acc2[mt][nt][2] + bvv) + xv.z;
            ov.w = gamma * (acc2[mt][nt][3] + bvv) + xv.w;
            *reinterpret_cast<float4*>(outb + base) = ov;
        }
    }
}

// ---------------- launch ----------------
extern "C" void kernel_launch(void* const* d_in, const int* in_sizes, int n_in,
                              void* d_out, int out_size, void* d_ws, size_t ws_size,
                              hipStream_t stream) {
    const float* x     = (const float*)d_in[0];
    const float* wf    = (const float*)d_in[1];
    const float* bf    = (const float*)d_in[2];
    const float* wg    = (const float*)d_in[3];
    const float* bg    = (const float*)d_in[4];
    const float* wh    = (const float*)d_in[5];
    const float* bh    = (const float*)d_in[6];
    const float* wv    = (const float*)d_in[7];
    const float* bv    = (const float*)d_in[8];
    const float* gamma = (const float*)d_in[9];
    float* out = (float*)d_out;
    char* ws = (char*)d_ws;

    unsigned short* f_ = (unsigned short*)(ws);                 //  4,194,304 B
    unsigned short* g_ = (unsigned short*)(ws + 4194304);       //  1,048,576 B
    unsigned short* h_ = (unsigned short*)(ws + 5242880);       //  4,194,304 B
    unsigned short* Wc = (unsigned short*)(ws + 26214400);      //     98,304 B
    unsigned short* Wv = (unsigned short*)(ws + 26312704);      //     65,536 B

    k_prep<<<192, 256, 0, stream>>>(wf, wg, wh, wv, Wc, Wv);
    k_conv_fgh<<<1024, 256, 0, stream>>>(x, Wc, bf, bg, bh, f_, g_, h_);
    k_attn<<<512, 512, 0, stream>>>(f_, g_, h_, Wv, bv, x, gamma, out);
}